// Round 10
// baseline (71.022 us; speedup 1.0000x reference)
//
#include <hip/hip_runtime.h>
#include <math.h>

// Lee Oscillator: per-element 100-step chaotic recurrence, time-max-pooled.
// Bitwise-matches jax/XLA-CPU f32 semantics (PROVEN: rounds 6-9 absmax=0.0).
// The arithmetic (xla_tanhf/xla_expf/fusion pattern) must not change.
//
// Round-10 structure (routing only, math untouched):
//  * t==1 classification by |sim0| > 0.21 (PROVEN subset of the round-9
//    predicate 2*damp < |omega|*2^-26: at s=0.21 margin is 22x and grows
//    like e^{500(s^2-0.0441)}; ~1-ulp exp wiggle cannot cross it). Slow
//    side is always correctness-neutral (loop returns omega by the lemma).
//  * k_scan removed: k_fill blocks self-scan bcount; last block writes total.
//  * k_process fuses 3 elements/thread (6 independent divide chains) for
//    ILP at ~1 wave/SIMD; 64-thread blocks for CU balance; tail via
//    index-clamp (duplicate writes of identical values, deterministic).

#define N_STEPS 100

typedef float v2f __attribute__((ext_vector_type(2)));
__device__ __forceinline__ v2f splat2(float s){ v2f v; v.x = s; v.y = s; return v; }
__device__ __forceinline__ unsigned umin_(unsigned a, unsigned b){ return a < b ? a : b; }

// (a1,a2,a3,a4,b1,b2,b3,b4,xi_E,xi_I,mu,e,k) for oscillator types 1..8 (f32)
__constant__ float PAR[8][13] = {
    { 0.0f,  5.0f,  5.0f,  1.0f,  0.0f, -1.0f,  1.0f,  0.0f, 0.0f, 0.0f, 5.0f, 0.001f, 500.0f},
    { 0.5f,  0.55f, 0.55f, -0.5f,  0.5f, -0.55f, -0.55f, -0.5f, 0.0f, 0.0f, 1.0f, 0.001f, 50.0f},
    { 0.5f,  0.6f,  0.55f,  0.5f, -0.5f, -0.6f,  -0.55f,  0.5f, 0.0f, 0.0f, 1.0f, 0.001f, 50.0f},
    {-0.5f,  0.55f, 0.55f, -0.5f, -0.5f, -0.55f, -0.55f,  0.5f, 0.0f, 0.0f, 1.0f, 0.001f, 50.0f},
    {-0.9f,  0.9f,  0.9f,  -0.9f,  0.9f, -0.9f,  -0.9f,   0.9f, 0.0f, 0.0f, 1.0f, 0.001f, 50.0f},
    {-0.9f,  0.9f,  0.9f,  -0.9f,  0.9f, -0.9f,  -0.9f,   0.9f, 0.0f, 0.0f, 1.0f, 0.001f, 300.0f},
    {-5.0f,  5.0f,  5.0f,  -5.0f,  1.0f, -1.0f,  -1.0f,   1.0f, 0.0f, 0.0f, 1.0f, 0.001f, 50.0f},
    {-5.0f,  5.0f,  5.0f,  -5.0f,  1.0f, -1.0f,  -1.0f,   1.0f, 0.0f, 0.0f, 1.0f, 0.001f, 300.0f},
};

// XLA CPU f32 tanh — scalar form. [bitwise-verified rounds 6-9]
__device__ __forceinline__ float xla_tanhf(float x) {
#pragma clang fp contract(off)
    float ax = fabsf(x);
    float xc = fminf(fmaxf(x, -7.99881172180175781f), 7.99881172180175781f);
    float x2 = xc * xc;
    float p = -2.76076847742355e-16f;
    p = fmaf(p, x2, 2.00018790482477e-13f);
    p = fmaf(p, x2, -8.60467152213735e-11f);
    p = fmaf(p, x2, 5.12229709037114e-08f);
    p = fmaf(p, x2, 1.48572235717979e-05f);
    p = fmaf(p, x2, 6.37261928875436e-04f);
    p = fmaf(p, x2, 4.89352455891786e-03f);
    float num = xc * p;
    float q = 1.19825839466702e-06f;
    q = fmaf(q, x2, 1.18534705686654e-04f);
    q = fmaf(q, x2, 2.26843463243900e-03f);
    q = fmaf(q, x2, 4.89352518554385e-03f);
    float r = num / q;                       // IEEE f32 divide
    return (ax < 0.0004f) ? x : r;
}

// Packed 2-wide tanh: SAME per-component IEEE ops. [bitwise-verified 8/9]
__device__ __forceinline__ v2f xla_tanh2(v2f x) {
#pragma clang fp contract(off)
    const float C = 7.99881172180175781f;
    v2f xc = __builtin_elementwise_min(__builtin_elementwise_max(x, splat2(-C)), splat2(C));
    v2f x2 = xc * xc;
    v2f p = splat2(-2.76076847742355e-16f);
    p = __builtin_elementwise_fma(p, x2, splat2(2.00018790482477e-13f));
    p = __builtin_elementwise_fma(p, x2, splat2(-8.60467152213735e-11f));
    p = __builtin_elementwise_fma(p, x2, splat2(5.12229709037114e-08f));
    p = __builtin_elementwise_fma(p, x2, splat2(1.48572235717979e-05f));
    p = __builtin_elementwise_fma(p, x2, splat2(6.37261928875436e-04f));
    p = __builtin_elementwise_fma(p, x2, splat2(4.89352455891786e-03f));
    v2f num = xc * p;
    v2f q = splat2(1.19825839466702e-06f);
    q = __builtin_elementwise_fma(q, x2, splat2(1.18534705686654e-04f));
    q = __builtin_elementwise_fma(q, x2, splat2(2.26843463243900e-03f));
    q = __builtin_elementwise_fma(q, x2, splat2(4.89352518554385e-03f));
    float rE = num.x / q.x;                  // IEEE f32 divides
    float rI = num.y / q.y;
    v2f r;
    r.x = (fabsf(x.x) < 0.0004f) ? x.x : rE;
    r.y = (fabsf(x.y) < 0.0004f) ? x.y : rI;
    return r;
}

// XLA CPU f32 exp (Cephes/Eigen pexp), FMA-contracted. [bitwise-verified]
__device__ __forceinline__ float xla_expf(float x) {
#pragma clang fp contract(off)
    float xc = fminf(fmaxf(x, -88.3762626647949f), 88.3762626647950f);
    float fx = floorf(fmaf(xc, 1.44269504088896341f, 0.5f));
    float r = fmaf(fx, -0.693359375f, xc);
    r = fmaf(fx, 2.12194440e-4f, r);
    float r2 = r * r;
    float y = 1.9875691500e-4f;
    y = fmaf(y, r, 1.3981999507e-3f);
    y = fmaf(y, r, 8.3334519073e-3f);
    y = fmaf(y, r, 4.1665795894e-2f);
    y = fmaf(y, r, 1.6666665459e-1f);
    y = fmaf(y, r, 5.0000001201e-1f);
    y = fmaf(y, r2, r);
    y = y + 1.0f;
    int n2 = (int)fx;
    float p2n = __int_as_float((n2 + 127) << 23);   // n==-127 -> +0.0
    return y * p2n;
}

// Shared per-element preamble (bitwise-identical everywhere).
__device__ __forceinline__ void preamble(float xv, const float* p,
                                         float& sim0, float& damp, float& omega) {
#pragma clang fp contract(off)
    float mu = p[10], e = p[11], k = p[12];
    float sgn  = (xv > 0.0f) ? 1.0f : ((xv < 0.0f) ? -1.0f : 0.0f);
    sim0 = fmaf(e, sgn, xv);                  // fadd(x, fmul(e,sgn)) fused
    float targ = (-k * sim0) * sim0;          // two plain muls
    damp  = xla_expf(targ);
    omega = xla_tanhf(mu * sim0);
}

// Full predicate (used for t != 1 and the monolithic fallback).
__device__ __forceinline__ bool fast_omega(float damp, float omega) {
    return (2.0f * damp) < (fabsf(omega) * 0x1p-26f);
}

// t==1 cheap classification: slow iff |sim0| <= 0.21 (see header proof).
__device__ __forceinline__ bool slow_t1(float xv, float e) {
#pragma clang fp contract(off)
    float sgn  = (xv > 0.0f) ? 1.0f : ((xv < 0.0f) ? -1.0f : 0.0f);
    float sim0 = fmaf(e, sgn, xv);
    return fabsf(sim0) <= 0.21f;
}

// 100-step loop, type-1, single element (fallback path). [bitwise-verified]
__device__ __forceinline__ float loop_t1(float sim0, float damp, float omega) {
#pragma clang fp contract(off)
    float E = 0.2f, I = 0.0f;
    float Dmax = -INFINITY;
    for (int s = 0; s < N_STEPS; ++s) {
        float tE = 5.0f * E;
        v2f mulc; mulc.x = -5.0f; mulc.y = -1.0f;
        v2f iv   = splat2(I);
        v2f addv; addv.x = tE;    addv.y = E;
        v2f u = __builtin_elementwise_fma(mulc, iv, addv);
        float sE = u.x + sim0;
        v2f pre; pre.x = sE; pre.y = u.y;
        v2f args = splat2(5.0f) * pre;
        v2f t = xla_tanh2(args);
        float D = t.x - t.y;
        Dmax = fmaxf(Dmax, D);
        E = t.x; I = t.y;
    }
    return fmaf(Dmax, damp, omega);
}

// 3-element fused type-1 loop: identical per-element ops, 3 independent
// chains (6 divides/step) interleaved by the scheduler for ILP.
__device__ __forceinline__ void loop_t1_x3(
    float s0, float d0, float o0,
    float s1, float d1, float o1,
    float s2, float d2, float o2,
    float& r0, float& r1, float& r2)
{
#pragma clang fp contract(off)
    float E0 = 0.2f, I0 = 0.0f, M0 = -INFINITY;
    float E1 = 0.2f, I1 = 0.0f, M1 = -INFINITY;
    float E2 = 0.2f, I2 = 0.0f, M2 = -INFINITY;
    v2f mulc; mulc.x = -5.0f; mulc.y = -1.0f;
    for (int s = 0; s < N_STEPS; ++s) {
        float tE0 = 5.0f * E0;
        float tE1 = 5.0f * E1;
        float tE2 = 5.0f * E2;
        v2f a0; a0.x = tE0; a0.y = E0;
        v2f a1; a1.x = tE1; a1.y = E1;
        v2f a2; a2.x = tE2; a2.y = E2;
        v2f u0 = __builtin_elementwise_fma(mulc, splat2(I0), a0);
        v2f u1 = __builtin_elementwise_fma(mulc, splat2(I1), a1);
        v2f u2 = __builtin_elementwise_fma(mulc, splat2(I2), a2);
        v2f p0; p0.x = u0.x + s0; p0.y = u0.y;
        v2f p1; p1.x = u1.x + s1; p1.y = u1.y;
        v2f p2; p2.x = u2.x + s2; p2.y = u2.y;
        v2f g0 = splat2(5.0f) * p0;
        v2f g1 = splat2(5.0f) * p1;
        v2f g2 = splat2(5.0f) * p2;
        v2f t0 = xla_tanh2(g0);
        v2f t1 = xla_tanh2(g1);
        v2f t2 = xla_tanh2(g2);
        float D0 = t0.x - t0.y;  M0 = fmaxf(M0, D0);  E0 = t0.x;  I0 = t0.y;
        float D1 = t1.x - t1.y;  M1 = fmaxf(M1, D1);  E1 = t1.x;  I1 = t1.y;
        float D2 = t2.x - t2.y;  M2 = fmaxf(M2, D2);  E2 = t2.x;  I2 = t2.y;
    }
    r0 = fmaf(M0, d0, o0);
    r1 = fmaf(M1, d1, o1);
    r2 = fmaf(M2, d2, o2);
}

// Generic-type loop (L feedback), proven scalar form.
__device__ __forceinline__ float loop_gen(const float* p, float sim0,
                                          float damp, float omega) {
#pragma clang fp contract(off)
    float a1 = p[0], a2 = p[1], a3 = p[2], a4 = p[3];
    float b1 = p[4], b2 = p[5], b3 = p[6], b4 = p[7];
    float xiE = p[8], xiI = p[9], mu = p[10];
    float nb2 = -b2;
    float E = 0.2f, I = 0.0f, L = 0.2f;
    float m = -INFINITY;
    for (int s = 0; s < N_STEPS; ++s) {
        float tE = a2 * E;
        float uE = fmaf(a1, L, tE);
        uE = fmaf(-a3, I, uE);
        uE = fmaf(a4, sim0, uE);
        uE = uE - xiE;
        float argE = mu * uE;
        float tI = nb2 * E;
        float uI = fmaf(b1, L, tI);
        uI = fmaf(-b3, I, uI);
        uI = fmaf(b4, sim0, uI);
        uI = uI - xiI;
        float argI = mu * uI;
        float E1 = xla_tanhf(argE);
        float I1 = xla_tanhf(argI);
        float d = E1 - I1;
        L = fmaf(d, damp, omega);
        E = E1; I = I1;
        m = fmaxf(m, L);
    }
    return m;
}

// Classification shared by k_count / k_fill (must agree EXACTLY).
__device__ __forceinline__ bool classify_slow(float xv, int t, const float* p) {
    if (t == 1) return slow_t1(xv, p[11]);
    float sim0, damp, omega;
    preamble(xv, p, sim0, damp, omega);
    return !fast_omega(damp, omega);
}

// ---------------- kernels ----------------

// 1) per-block slow-lane count
__global__ __launch_bounds__(256)
void k_count(const float* __restrict__ x, const int* __restrict__ osc_type,
             unsigned* __restrict__ bcount, int n)
{
    __shared__ unsigned wc[4];
    int i = blockIdx.x * 256 + threadIdx.x;
    int t = *osc_type;
    const float* p = PAR[t - 1];
    bool slow = (i < n) && classify_slow(x[i], t, p);
    unsigned long long mask = __ballot(slow);
    int lane = threadIdx.x & 63, wid = threadIdx.x >> 6;
    if (lane == 0) wc[wid] = (unsigned)__popcll(mask);
    __syncthreads();
    if (threadIdx.x == 0) bcount[blockIdx.x] = wc[0] + wc[1] + wc[2] + wc[3];
}

// 2) fill: self-scan bcount for this block's base; fast lanes -> out=omega;
//    slow lanes -> wl[base + local prefix]; last block writes bcount[NB]=total.
__global__ __launch_bounds__(256)
void k_fill(const float* __restrict__ x, const int* __restrict__ osc_type,
            float* __restrict__ out, unsigned* __restrict__ bcount,
            unsigned* __restrict__ wl, int n, int NB)
{
#pragma clang fp contract(off)
    __shared__ unsigned sums[256];
    __shared__ unsigned woff[4];
    int tid = threadIdx.x;
    int bid = blockIdx.x;

    // self-scan: base = sum of bcount[0..bid)
    unsigned s = 0;
    for (int j = tid; j < bid; j += 256) s += bcount[j];
    sums[tid] = s;
    __syncthreads();
    for (int off = 128; off > 0; off >>= 1) {
        if (tid < off) sums[tid] += sums[tid + off];
        __syncthreads();
    }
    unsigned bbase = sums[0];

    int i = bid * 256 + tid;
    bool active = (i < n);
    int t = *osc_type;
    const float* p = PAR[t - 1];
    float xv = active ? x[i] : 1.0e9f;          // 1e9 -> fast (and inactive)
    bool slow = active && classify_slow(xv, t, p);
    if (active && !slow) {
        // omega, computed exactly as in preamble
        float mu = p[10], e = p[11];
        float sgn  = (xv > 0.0f) ? 1.0f : ((xv < 0.0f) ? -1.0f : 0.0f);
        float sim0 = fmaf(e, sgn, xv);
        out[i] = xla_tanhf(mu * sim0);
    }
    unsigned long long mask = __ballot(slow);
    int lane = tid & 63, wid = tid >> 6;
    if (lane == 0) woff[wid] = (unsigned)__popcll(mask);
    __syncthreads();
    if (slow) {
        unsigned base = bbase;
        for (int w = 0; w < wid; ++w) base += woff[w];
        base += (unsigned)__popcll(mask & ((1ull << lane) - 1ull));
        wl[base] = (unsigned)i;
    }
    if (tid == 0 && bid == NB - 1)
        bcount[NB] = bbase + woff[0] + woff[1] + woff[2] + woff[3];
}

// 3) dense worklist, 3 fused elements/thread, 64-thread blocks.
__global__ __launch_bounds__(64)
void k_process(const float* __restrict__ x, const int* __restrict__ osc_type,
               float* __restrict__ out, const unsigned* __restrict__ total_p,
               const unsigned* __restrict__ wl)
{
#pragma clang fp contract(off)
    unsigned total = *total_p;
    if (total == 0) return;
    int t = *osc_type;
    const float* p = PAR[t - 1];
    unsigned ntri = (total + 2u) / 3u;
    unsigned nthreads = gridDim.x * 64u;
    for (unsigned tri = blockIdx.x * 64u + threadIdx.x; tri < ntri; tri += nthreads) {
        unsigned b = tri * 3u;
        unsigned e0 = b;
        unsigned e1 = umin_(b + 1u, total - 1u);
        unsigned e2 = umin_(b + 2u, total - 1u);
        int i0 = (int)wl[e0], i1 = (int)wl[e1], i2 = (int)wl[e2];
        if (t == 1) {
            float s0,d0,o0, s1,d1,o1, s2,d2,o2;
            preamble(x[i0], p, s0, d0, o0);
            preamble(x[i1], p, s1, d1, o1);
            preamble(x[i2], p, s2, d2, o2);
            float r0, r1, r2;
            loop_t1_x3(s0,d0,o0, s1,d1,o1, s2,d2,o2, r0, r1, r2);
            out[i0] = r0; out[i1] = r1; out[i2] = r2;   // dups write same bits
        } else {
            for (unsigned c = 0; c < 3u; ++c) {
                unsigned idx = b + c;
                if (idx < total) {
                    int i = (int)wl[idx];
                    float sim0, damp, omega;
                    preamble(x[i], p, sim0, damp, omega);
                    out[i] = loop_gen(p, sim0, damp, omega);
                }
            }
        }
    }
}

// Fallback: proven monolithic kernel (if ws too small).
__global__ __launch_bounds__(256)
void k_monolithic(const float* __restrict__ x, const int* __restrict__ osc_type,
                  float* __restrict__ out, int n)
{
#pragma clang fp contract(off)
    int i = blockIdx.x * 256 + threadIdx.x;
    if (i >= n) return;
    int t = *osc_type;
    const float* p = PAR[t - 1];
    float sim0, damp, omega;
    preamble(x[i], p, sim0, damp, omega);
    if (fast_omega(damp, omega)) { out[i] = omega; return; }
    out[i] = (t == 1) ? loop_t1(sim0, damp, omega)
                      : loop_gen(p, sim0, damp, omega);
}

extern "C" void kernel_launch(void* const* d_in, const int* in_sizes, int n_in,
                              void* d_out, int out_size, void* d_ws, size_t ws_size,
                              hipStream_t stream) {
    const float* x        = (const float*)d_in[0];
    const int*   osc_type = (const int*)d_in[1];
    float*       out      = (float*)d_out;
    int n = in_sizes[0];
    int NB = (n + 255) / 256;

    size_t needed = ((size_t)NB + 1 + (size_t)n) * sizeof(unsigned);
    if (ws_size >= needed) {
        unsigned* bcount = (unsigned*)d_ws;      // NB+1 entries ([NB] = total)
        unsigned* wl     = bcount + NB + 1;      // n entries
        k_count  <<<NB, 256, 0, stream>>>(x, osc_type, bcount, n);
        k_fill   <<<NB, 256, 0, stream>>>(x, osc_type, out, bcount, wl, n, NB);
        k_process<<<2048, 64, 0, stream>>>(x, osc_type, out, bcount + NB, wl);
    } else {
        k_monolithic<<<NB, 256, 0, stream>>>(x, osc_type, out, n);
    }
}

// Round 11
// 48.856 us; speedup vs baseline: 1.4537x; 1.4537x over previous
//
#include <hip/hip_runtime.h>
#include <math.h>

// Lee Oscillator: per-element 100-step chaotic recurrence, time-max-pooled.
// Bitwise-matches jax/XLA-CPU f32 semantics (PROVEN: rounds 6-10 absmax=0.0).
// The arithmetic (xla_tanhf/xla_expf/fusion pattern) must not change.
//
// Round-11: revert round-10's 3-elem fusion (f32 IEEE divides serialize on
// VCC within a wave -> in-thread ILP across divides is nil; fusion only
// destroyed TLP: 0.8 waves/SIMD, VALUBusy 32%). Back to 1 elem/thread
// (2.4 waves/SIMD) with 64-thread workgroups for finest balance. Keep
// round-10's cheap t==1 classification and scan-free k_fill.

#define N_STEPS 100

typedef float v2f __attribute__((ext_vector_type(2)));
__device__ __forceinline__ v2f splat2(float s){ v2f v; v.x = s; v.y = s; return v; }

// (a1,a2,a3,a4,b1,b2,b3,b4,xi_E,xi_I,mu,e,k) for oscillator types 1..8 (f32)
__constant__ float PAR[8][13] = {
    { 0.0f,  5.0f,  5.0f,  1.0f,  0.0f, -1.0f,  1.0f,  0.0f, 0.0f, 0.0f, 5.0f, 0.001f, 500.0f},
    { 0.5f,  0.55f, 0.55f, -0.5f,  0.5f, -0.55f, -0.55f, -0.5f, 0.0f, 0.0f, 1.0f, 0.001f, 50.0f},
    { 0.5f,  0.6f,  0.55f,  0.5f, -0.5f, -0.6f,  -0.55f,  0.5f, 0.0f, 0.0f, 1.0f, 0.001f, 50.0f},
    {-0.5f,  0.55f, 0.55f, -0.5f, -0.5f, -0.55f, -0.55f,  0.5f, 0.0f, 0.0f, 1.0f, 0.001f, 50.0f},
    {-0.9f,  0.9f,  0.9f,  -0.9f,  0.9f, -0.9f,  -0.9f,   0.9f, 0.0f, 0.0f, 1.0f, 0.001f, 50.0f},
    {-0.9f,  0.9f,  0.9f,  -0.9f,  0.9f, -0.9f,  -0.9f,   0.9f, 0.0f, 0.0f, 1.0f, 0.001f, 300.0f},
    {-5.0f,  5.0f,  5.0f,  -5.0f,  1.0f, -1.0f,  -1.0f,   1.0f, 0.0f, 0.0f, 1.0f, 0.001f, 50.0f},
    {-5.0f,  5.0f,  5.0f,  -5.0f,  1.0f, -1.0f,  -1.0f,   1.0f, 0.0f, 0.0f, 1.0f, 0.001f, 300.0f},
};

// XLA CPU f32 tanh — scalar form. [bitwise-verified rounds 6-10]
__device__ __forceinline__ float xla_tanhf(float x) {
#pragma clang fp contract(off)
    float ax = fabsf(x);
    float xc = fminf(fmaxf(x, -7.99881172180175781f), 7.99881172180175781f);
    float x2 = xc * xc;
    float p = -2.76076847742355e-16f;
    p = fmaf(p, x2, 2.00018790482477e-13f);
    p = fmaf(p, x2, -8.60467152213735e-11f);
    p = fmaf(p, x2, 5.12229709037114e-08f);
    p = fmaf(p, x2, 1.48572235717979e-05f);
    p = fmaf(p, x2, 6.37261928875436e-04f);
    p = fmaf(p, x2, 4.89352455891786e-03f);
    float num = xc * p;
    float q = 1.19825839466702e-06f;
    q = fmaf(q, x2, 1.18534705686654e-04f);
    q = fmaf(q, x2, 2.26843463243900e-03f);
    q = fmaf(q, x2, 4.89352518554385e-03f);
    float r = num / q;                       // IEEE f32 divide
    return (ax < 0.0004f) ? x : r;
}

// Packed 2-wide tanh: SAME per-component IEEE ops. [bitwise-verified 8-10]
__device__ __forceinline__ v2f xla_tanh2(v2f x) {
#pragma clang fp contract(off)
    const float C = 7.99881172180175781f;
    v2f xc = __builtin_elementwise_min(__builtin_elementwise_max(x, splat2(-C)), splat2(C));
    v2f x2 = xc * xc;
    v2f p = splat2(-2.76076847742355e-16f);
    p = __builtin_elementwise_fma(p, x2, splat2(2.00018790482477e-13f));
    p = __builtin_elementwise_fma(p, x2, splat2(-8.60467152213735e-11f));
    p = __builtin_elementwise_fma(p, x2, splat2(5.12229709037114e-08f));
    p = __builtin_elementwise_fma(p, x2, splat2(1.48572235717979e-05f));
    p = __builtin_elementwise_fma(p, x2, splat2(6.37261928875436e-04f));
    p = __builtin_elementwise_fma(p, x2, splat2(4.89352455891786e-03f));
    v2f num = xc * p;
    v2f q = splat2(1.19825839466702e-06f);
    q = __builtin_elementwise_fma(q, x2, splat2(1.18534705686654e-04f));
    q = __builtin_elementwise_fma(q, x2, splat2(2.26843463243900e-03f));
    q = __builtin_elementwise_fma(q, x2, splat2(4.89352518554385e-03f));
    float rE = num.x / q.x;                  // IEEE f32 divides
    float rI = num.y / q.y;
    v2f r;
    r.x = (fabsf(x.x) < 0.0004f) ? x.x : rE;
    r.y = (fabsf(x.y) < 0.0004f) ? x.y : rI;
    return r;
}

// XLA CPU f32 exp (Cephes/Eigen pexp), FMA-contracted. [bitwise-verified]
__device__ __forceinline__ float xla_expf(float x) {
#pragma clang fp contract(off)
    float xc = fminf(fmaxf(x, -88.3762626647949f), 88.3762626647950f);
    float fx = floorf(fmaf(xc, 1.44269504088896341f, 0.5f));
    float r = fmaf(fx, -0.693359375f, xc);
    r = fmaf(fx, 2.12194440e-4f, r);
    float r2 = r * r;
    float y = 1.9875691500e-4f;
    y = fmaf(y, r, 1.3981999507e-3f);
    y = fmaf(y, r, 8.3334519073e-3f);
    y = fmaf(y, r, 4.1665795894e-2f);
    y = fmaf(y, r, 1.6666665459e-1f);
    y = fmaf(y, r, 5.0000001201e-1f);
    y = fmaf(y, r2, r);
    y = y + 1.0f;
    int n2 = (int)fx;
    float p2n = __int_as_float((n2 + 127) << 23);   // n==-127 -> +0.0
    return y * p2n;
}

// Shared per-element preamble (bitwise-identical everywhere).
__device__ __forceinline__ void preamble(float xv, const float* p,
                                         float& sim0, float& damp, float& omega) {
#pragma clang fp contract(off)
    float mu = p[10], e = p[11], k = p[12];
    float sgn  = (xv > 0.0f) ? 1.0f : ((xv < 0.0f) ? -1.0f : 0.0f);
    sim0 = fmaf(e, sgn, xv);                  // fadd(x, fmul(e,sgn)) fused
    float targ = (-k * sim0) * sim0;          // two plain muls
    damp  = xla_expf(targ);
    omega = xla_tanhf(mu * sim0);
}

// Full predicate (t != 1 and monolithic fallback). PROVEN lemma (round 9):
// 2*damp < |omega|*2^-26 with |D|<2 => fma(D,damp,omega)==omega every step.
__device__ __forceinline__ bool fast_omega(float damp, float omega) {
    return (2.0f * damp) < (fabsf(omega) * 0x1p-26f);
}

// t==1 cheap classification: slow iff |sim0| <= 0.21. PROVEN subset of the
// predicate above (22x margin at the boundary; grows like e^{500(s^2-0.0441)}).
// Slow-side routing is always correctness-neutral (loop returns omega).
__device__ __forceinline__ bool slow_t1(float xv, float e) {
#pragma clang fp contract(off)
    float sgn  = (xv > 0.0f) ? 1.0f : ((xv < 0.0f) ? -1.0f : 0.0f);
    float sim0 = fmaf(e, sgn, xv);
    return fabsf(sim0) <= 0.21f;
}

// 100-step loop, type-1 specialization (a1=b1=0, a4=1, xi=0), pk-packed.
// Per-component ops bitwise-identical to the round-6 verified scalar loop.
__device__ __forceinline__ float loop_t1(float sim0, float damp, float omega) {
#pragma clang fp contract(off)
    float E = 0.2f, I = 0.0f;
    float Dmax = -INFINITY;
    for (int s = 0; s < N_STEPS; ++s) {
        float tE = 5.0f * E;                   // round(a2*E)  (0*L unfolded)
        v2f mulc; mulc.x = -5.0f; mulc.y = -1.0f;
        v2f iv   = splat2(I);
        v2f addv; addv.x = tE;    addv.y = E;
        v2f u = __builtin_elementwise_fma(mulc, iv, addv);  // (uE, E-I)
        float sE = u.x + sim0;                 // plain fadd (a4==1 folded)
        v2f pre; pre.x = sE; pre.y = u.y;
        v2f args = splat2(5.0f) * pre;         // (argE, argI)
        v2f t = xla_tanh2(args);
        float D = t.x - t.y;                   // plain fsub
        Dmax = fmaxf(Dmax, D);
        E = t.x; I = t.y;
    }
    return fmaf(Dmax, damp, omega);            // == max_t fma(D_t,damp,omega)
}

// Generic-type loop (L feedback), proven scalar form.
__device__ __forceinline__ float loop_gen(const float* p, float sim0,
                                          float damp, float omega) {
#pragma clang fp contract(off)
    float a1 = p[0], a2 = p[1], a3 = p[2], a4 = p[3];
    float b1 = p[4], b2 = p[5], b3 = p[6], b4 = p[7];
    float xiE = p[8], xiI = p[9], mu = p[10];
    float nb2 = -b2;
    float E = 0.2f, I = 0.0f, L = 0.2f;
    float m = -INFINITY;
    for (int s = 0; s < N_STEPS; ++s) {
        float tE = a2 * E;
        float uE = fmaf(a1, L, tE);
        uE = fmaf(-a3, I, uE);
        uE = fmaf(a4, sim0, uE);
        uE = uE - xiE;
        float argE = mu * uE;
        float tI = nb2 * E;
        float uI = fmaf(b1, L, tI);
        uI = fmaf(-b3, I, uI);
        uI = fmaf(b4, sim0, uI);
        uI = uI - xiI;
        float argI = mu * uI;
        float E1 = xla_tanhf(argE);
        float I1 = xla_tanhf(argI);
        float d = E1 - I1;
        L = fmaf(d, damp, omega);
        E = E1; I = I1;
        m = fmaxf(m, L);
    }
    return m;
}

// Classification shared by k_count / k_fill (must agree EXACTLY).
__device__ __forceinline__ bool classify_slow(float xv, int t, const float* p) {
    if (t == 1) return slow_t1(xv, p[11]);
    float sim0, damp, omega;
    preamble(xv, p, sim0, damp, omega);
    return !fast_omega(damp, omega);
}

// ---------------- kernels ----------------

// 1) per-block slow-lane count (ballot + popc, no atomics)
__global__ __launch_bounds__(256)
void k_count(const float* __restrict__ x, const int* __restrict__ osc_type,
             unsigned* __restrict__ bcount, int n)
{
    __shared__ unsigned wc[4];
    int i = blockIdx.x * 256 + threadIdx.x;
    int t = *osc_type;
    const float* p = PAR[t - 1];
    bool slow = (i < n) && classify_slow(x[i], t, p);
    unsigned long long mask = __ballot(slow);
    int lane = threadIdx.x & 63, wid = threadIdx.x >> 6;
    if (lane == 0) wc[wid] = (unsigned)__popcll(mask);
    __syncthreads();
    if (threadIdx.x == 0) bcount[blockIdx.x] = wc[0] + wc[1] + wc[2] + wc[3];
}

// 2) fill: self-scan bcount for this block's base; fast lanes -> out=omega;
//    slow lanes -> wl[base + local prefix]; last block writes bcount[NB]=total.
__global__ __launch_bounds__(256)
void k_fill(const float* __restrict__ x, const int* __restrict__ osc_type,
            float* __restrict__ out, unsigned* __restrict__ bcount,
            unsigned* __restrict__ wl, int n, int NB)
{
#pragma clang fp contract(off)
    __shared__ unsigned sums[256];
    __shared__ unsigned woff[4];
    int tid = threadIdx.x;
    int bid = blockIdx.x;

    // self-scan: base = sum of bcount[0..bid)
    unsigned s = 0;
    for (int j = tid; j < bid; j += 256) s += bcount[j];
    sums[tid] = s;
    __syncthreads();
    for (int off = 128; off > 0; off >>= 1) {
        if (tid < off) sums[tid] += sums[tid + off];
        __syncthreads();
    }
    unsigned bbase = sums[0];

    int i = bid * 256 + tid;
    bool active = (i < n);
    int t = *osc_type;
    const float* p = PAR[t - 1];
    float xv = active ? x[i] : 1.0e9f;          // 1e9 -> fast (and inactive)
    bool slow = active && classify_slow(xv, t, p);
    if (active && !slow) {
        // omega, computed exactly as in preamble
        float mu = p[10], e = p[11];
        float sgn  = (xv > 0.0f) ? 1.0f : ((xv < 0.0f) ? -1.0f : 0.0f);
        float sim0 = fmaf(e, sgn, xv);
        out[i] = xla_tanhf(mu * sim0);
    }
    unsigned long long mask = __ballot(slow);
    int lane = tid & 63, wid = tid >> 6;
    if (lane == 0) woff[wid] = (unsigned)__popcll(mask);
    __syncthreads();
    if (slow) {
        unsigned base = bbase;
        for (int w = 0; w < wid; ++w) base += woff[w];
        base += (unsigned)__popcll(mask & ((1ull << lane) - 1ull));
        wl[base] = (unsigned)i;
    }
    if (tid == 0 && bid == NB - 1)
        bcount[NB] = bbase + woff[0] + woff[1] + woff[2] + woff[3];
}

// 3) dense worklist: 1 element/thread (max TLP — divide latency is hidden
//    only by waves/SIMD; VCC serialization kills in-thread divide ILP),
//    64-thread workgroups for finest CU balance, grid-stride for safety.
__global__ __launch_bounds__(64)
void k_process(const float* __restrict__ x, const int* __restrict__ osc_type,
               float* __restrict__ out, const unsigned* __restrict__ total_p,
               const unsigned* __restrict__ wl)
{
#pragma clang fp contract(off)
    unsigned total = *total_p;
    int t = *osc_type;
    const float* p = PAR[t - 1];
    unsigned stride = gridDim.x * 64u;
    for (unsigned tid = blockIdx.x * 64u + threadIdx.x; tid < total; tid += stride) {
        int i = (int)wl[tid];
        float sim0, damp, omega;
        preamble(x[i], p, sim0, damp, omega);
        out[i] = (t == 1) ? loop_t1(sim0, damp, omega)
                          : loop_gen(p, sim0, damp, omega);
    }
}

// Fallback: proven monolithic kernel (if ws too small).
__global__ __launch_bounds__(256)
void k_monolithic(const float* __restrict__ x, const int* __restrict__ osc_type,
                  float* __restrict__ out, int n)
{
#pragma clang fp contract(off)
    int i = blockIdx.x * 256 + threadIdx.x;
    if (i >= n) return;
    int t = *osc_type;
    const float* p = PAR[t - 1];
    float sim0, damp, omega;
    preamble(x[i], p, sim0, damp, omega);
    if (fast_omega(damp, omega)) { out[i] = omega; return; }
    out[i] = (t == 1) ? loop_t1(sim0, damp, omega)
                      : loop_gen(p, sim0, damp, omega);
}

extern "C" void kernel_launch(void* const* d_in, const int* in_sizes, int n_in,
                              void* d_out, int out_size, void* d_ws, size_t ws_size,
                              hipStream_t stream) {
    const float* x        = (const float*)d_in[0];
    const int*   osc_type = (const int*)d_in[1];
    float*       out      = (float*)d_out;
    int n = in_sizes[0];
    int NB = (n + 255) / 256;

    size_t needed = ((size_t)NB + 1 + (size_t)n) * sizeof(unsigned);
    if (ws_size >= needed) {
        unsigned* bcount = (unsigned*)d_ws;      // NB+1 entries ([NB] = total)
        unsigned* wl     = bcount + NB + 1;      // n entries
        k_count  <<<NB, 256, 0, stream>>>(x, osc_type, bcount, n);
        k_fill   <<<NB, 256, 0, stream>>>(x, osc_type, out, bcount, wl, n, NB);
        k_process<<<4096, 64, 0, stream>>>(x, osc_type, out, bcount + NB, wl);
    } else {
        k_monolithic<<<NB, 256, 0, stream>>>(x, osc_type, out, n);
    }
}